// Round 1
// baseline (537.483 us; speedup 1.0000x reference)
//
#include <hip/hip_runtime.h>

// SpectralConv1d fused: rfft(T=64, modes 16) -> complex channel mix -> irfft,
// all as bf16 MFMA (16x16x32). One block per n (1024 blocks, 512 threads).
// d_ws holds weights repacked to fragment-linear bf16 with irfft coeff folded.

typedef __attribute__((ext_vector_type(8))) short  bf16x8_t;  // 8 bf16 (4 VGPR)
typedef __attribute__((ext_vector_type(4))) short  bf16x4_t;
typedef __attribute__((ext_vector_type(4))) float  f32x4_t;
typedef __attribute__((ext_vector_type(2))) float  f32x2_t;

#define PI2_64 0.09817477042f  // 2*pi/64

__device__ __forceinline__ unsigned short f2bf(float f) {
  unsigned u = __float_as_uint(f);
  u = u + 0x7FFFu + ((u >> 16) & 1u);   // RNE to bf16
  return (unsigned short)(u >> 16);
}

__device__ __forceinline__ bf16x8_t join8(bf16x4_t lo, bf16x4_t hi) {
  bf16x8_t f;
  f[0] = lo[0]; f[1] = lo[1]; f[2] = lo[2]; f[3] = lo[3];
  f[4] = hi[0]; f[5] = hi[1]; f[6] = hi[2]; f[7] = hi[3];
  return f;
}

// ---------------------------------------------------------------------------
// Repack weights1 [C=64][O=64][M=16][2] f32 -> W2 bf16, fragment-linear:
// W2[m][kt(4)][Nt(8)][lane(64)][e(8)], value = Wtil_m[ kk ][ oo ] * cm
//   kk = kt*32 + 4*(lane>>4) + (e&3) + 16*(e>>2)   (k-dim: ri*64+c, ri0=Fr,ri1=Fi)
//   oo = Nt*16 + (lane&15)                          (n-dim: ro*64+o, ro0=Or,ro1=Oi)
//   Wtil: (Fr->Or)=wr  (Fi->Or)=-wi  (Fr->Oi)=wi  (Fi->Oi)=wr
//   cm = (m==0 ? 1 : 2)/64  (irfft coefficient, folded here)
// ---------------------------------------------------------------------------
__global__ void repack_w(const float* __restrict__ w1, short* __restrict__ W2) {
  int i = blockIdx.x * 256 + threadIdx.x;          // 0 .. 262143
  int e    = i & 7;
  int lane = (i >> 3) & 63;
  int Nt   = (i >> 9) & 7;
  int kt   = (i >> 12) & 3;
  int m    = i >> 14;
  int g = lane >> 4, l15 = lane & 15;
  int kk = kt * 32 + 4 * g + (e & 3) + 16 * (e >> 2);
  int oo = Nt * 16 + l15;
  int ri = kk >> 6, c = kk & 63;
  int ro = oo >> 6, o = oo & 63;
  float wr = w1[((c * 64 + o) * 16 + m) * 2 + 0];
  float wi = w1[((c * 64 + o) * 16 + m) * 2 + 1];
  float v = (ri == 0) ? ((ro == 0) ? wr : wi)
                      : ((ro == 0) ? -wi : wr);
  v *= (m == 0 ? 1.0f : 2.0f) / 64.0f;
  W2[i] = (short)f2bf(v);
}

// ---------------------------------------------------------------------------
// Fused kernel. LDS 128 KiB:
//   fsb (64K): F  as [m(16)][k4(32)][slot(16)][j(4)] bf16, slot = nd ^ (k4&15)
//   bbf (64K): phase 1: x-tile  [tblk(8)][col(1024)][t4(4)] bf16 (col = d*64+c)
//              phase 2: OF      [m4(8)][col(1024)][j(4)]   bf16 (col = d*64+o)
// k-slot map everywhere: koff(g,e) = 4g + (e&3) + 16*(e>>2)
// ---------------------------------------------------------------------------
__global__ __launch_bounds__(512, 2)
void spectral_fused(const float* __restrict__ x, const short* __restrict__ W2,
                    float* __restrict__ out) {
  __shared__ __align__(16) short fsb[32768];
  __shared__ __align__(16) short bbf[32768];

  const int tid = threadIdx.x;
  const int n   = blockIdx.x;
  const int w   = tid >> 6;      // wave 0..7
  const int l   = tid & 63;
  const int g   = l >> 4;        // lane group 0..3
  const int l15 = l & 15;

  // ---- basis fragments in registers (A operands) ----
  // Stage 1: B32[m~F(32) x t(64)], rows 0..15 = cos, 16..31 = -sin. A-row = l15.
  bf16x8_t a1[2][2];   // [pass][mt]; element e -> t = pass*32 + koff(g,e)
#pragma unroll
  for (int pass = 0; pass < 2; ++pass)
#pragma unroll
    for (int mt = 0; mt < 2; ++mt) {
      bf16x8_t f;
#pragma unroll
      for (int e = 0; e < 8; ++e) {
        int t = pass * 32 + 4 * g + (e & 3) + 16 * (e >> 2);
        int k = (l15 * t) & 63;
        float s, c;
        __sincosf(k * PI2_64, &s, &c);
        f[e] = (short)f2bf(mt == 0 ? c : -s);
      }
      a1[pass][mt] = f;
    }
  // Stage 3: IB[t(64) x m~(32)]; m~ = koff(g,e): e<4 -> cos, e>=4 -> -sin (cm in W2).
  bf16x8_t a3[4];      // [mt]; A-row = t = mt*16 + l15
#pragma unroll
  for (int mt = 0; mt < 4; ++mt) {
    bf16x8_t f;
#pragma unroll
    for (int e = 0; e < 8; ++e) {
      int t = mt * 16 + l15;
      int m = 4 * g + (e & 3);
      int k = (m * t) & 63;
      float s, c;
      __sincosf(k * PI2_64, &s, &c);
      f[e] = (short)f2bf(e < 4 ? c : -s);
    }
    a3[mt] = f;
  }

  // ---- Stage 1: DFT. acc over 2 passes of 32 t. ----
  f32x4_t acc1[2][8];
#pragma unroll
  for (int mt = 0; mt < 2; ++mt)
#pragma unroll
    for (int i = 0; i < 8; ++i) acc1[mt][i] = (f32x4_t){0.f, 0.f, 0.f, 0.f};

  const float* xn = x + (size_t)n * 1024;

#pragma unroll 1
  for (int pass = 0; pass < 2; ++pass) {
    // stage 32 t-rows into bbf: [tblk][col][t4]; thread owns cols {2tid, 2tid+1}
#pragma unroll
    for (int tb = 0; tb < 8; ++tb) {
      f32x2_t v[4];
#pragma unroll
      for (int j = 0; j < 4; ++j) {
        int trow = pass * 32 + tb * 4 + j;
        v[j] = *reinterpret_cast<const f32x2_t*>(xn + (size_t)trow * 1048576 + 2 * tid);
      }
      bf16x4_t pa, pb;
#pragma unroll
      for (int j = 0; j < 4; ++j) {
        pa[j] = (short)f2bf(v[j][0]);
        pb[j] = (short)f2bf(v[j][1]);
      }
      *reinterpret_cast<bf16x4_t*>(&bbf[tb * 4096 + (2 * tid) * 4]) = pa;
      *reinterpret_cast<bf16x4_t*>(&bbf[tb * 4096 + (2 * tid + 1) * 4]) = pb;
    }
    __syncthreads();
    // MFMA: wave w owns Nt = w*8 .. w*8+7 (col = Nt*16 + l15 = d*64 + c)
#pragma unroll
    for (int Nti = 0; Nti < 8; ++Nti) {
      int col = (w * 8 + Nti) * 16 + l15;
      bf16x4_t lo = *reinterpret_cast<const bf16x4_t*>(&bbf[g * 4096 + col * 4]);
      bf16x4_t hi = *reinterpret_cast<const bf16x4_t*>(&bbf[(4 + g) * 4096 + col * 4]);
      bf16x8_t bf = join8(lo, hi);
#pragma unroll
      for (int mt = 0; mt < 2; ++mt)
        acc1[mt][Nti] =
            __builtin_amdgcn_mfma_f32_16x16x32_bf16(a1[pass][mt], bf, acc1[mt][Nti], 0, 0, 0);
    }
    __syncthreads();
  }

  // ---- write F to fsb: [m][k4][slot][j], k~ = k4*4+j = ri*64+c, slot = nd^(k4&15) ----
#pragma unroll
  for (int mt = 0; mt < 2; ++mt)
#pragma unroll
    for (int Nti = 0; Nti < 8; ++Nti) {
      int Nt = w * 8 + Nti;
      int nd = Nt >> 2, cc = Nt & 3;
      int c  = cc * 16 + l15;
      int k4 = mt * 16 + (c >> 2);
      int slot = nd ^ (k4 & 15);
#pragma unroll
      for (int r = 0; r < 4; ++r) {
        int m = 4 * g + r;                       // C/D row = 4g + reg
        fsb[m * 2048 + k4 * 64 + slot * 4 + (c & 3)] = (short)f2bf(acc1[mt][Nti][r]);
      }
    }
  __syncthreads();

  // ---- Stage 2: per m, [Fr|Fi](16nd x 128) x Wtil(128 x 128); wave w owns o~tile w ----
  {
    int rio = w >> 2;
    int o   = (w & 3) * 16 + l15;
#pragma unroll 1
    for (int m = 0; m < 16; ++m) {
      f32x4_t acc = (f32x4_t){0.f, 0.f, 0.f, 0.f};
#pragma unroll
      for (int kt = 0; kt < 4; ++kt) {
        int k4a = kt * 8 + g, k4b = kt * 8 + 4 + g;
        bf16x4_t lo = *reinterpret_cast<const bf16x4_t*>(
            &fsb[m * 2048 + k4a * 64 + (l15 ^ (k4a & 15)) * 4]);
        bf16x4_t hi = *reinterpret_cast<const bf16x4_t*>(
            &fsb[m * 2048 + k4b * 64 + (l15 ^ (k4b & 15)) * 4]);
        bf16x8_t fa = join8(lo, hi);
        bf16x8_t wf = *reinterpret_cast<const bf16x8_t*>(
            W2 + (size_t)(((m * 4 + kt) * 8 + w) * 64 + l) * 8);
        acc = __builtin_amdgcn_mfma_f32_16x16x32_bf16(fa, wf, acc, 0, 0, 0);
      }
      // OF write: bbf as [m4][col][j], m~ = rio*16 + m, col = nd*64 + o
#pragma unroll
      for (int r = 0; r < 4; ++r) {
        int nd = 4 * g + r;
        int mm = rio * 16 + m;
        bbf[(mm >> 2) * 4096 + (nd * 64 + o) * 4 + (mm & 3)] = (short)f2bf(acc[r]);
      }
    }
  }
  __syncthreads();

  // ---- Stage 3: out(64t x col) = IB(64x32) * OF(32 x col); 1 MFMA per (mt,Nt) ----
  float* on = out + (size_t)n * 1024;
#pragma unroll
  for (int Nti = 0; Nti < 8; ++Nti) {
    int col = (w * 8 + Nti) * 16 + l15;          // = d*64 + o
    bf16x4_t lo = *reinterpret_cast<const bf16x4_t*>(&bbf[g * 4096 + col * 4]);
    bf16x4_t hi = *reinterpret_cast<const bf16x4_t*>(&bbf[(4 + g) * 4096 + col * 4]);
    bf16x8_t bf = join8(lo, hi);
#pragma unroll
    for (int mt = 0; mt < 4; ++mt) {
      f32x4_t acc = (f32x4_t){0.f, 0.f, 0.f, 0.f};
      acc = __builtin_amdgcn_mfma_f32_16x16x32_bf16(a3[mt], bf, acc, 0, 0, 0);
#pragma unroll
      for (int r = 0; r < 4; ++r) {
        int t = mt * 16 + 4 * g + r;
        on[(size_t)t * 1048576 + col] = acc[r];
      }
    }
  }
}

extern "C" void kernel_launch(void* const* d_in, const int* in_sizes, int n_in,
                              void* d_out, int out_size, void* d_ws, size_t ws_size,
                              hipStream_t stream) {
  const float* x  = (const float*)d_in[0];   // [64][1024][16][64] f32
  const float* w1 = (const float*)d_in[1];   // [64][64][16][2] f32
  float* o = (float*)d_out;                  // [64][1024][16][64] f32
  short* W2 = (short*)d_ws;                  // 262144 bf16 = 512 KiB

  repack_w<<<dim3(1024), dim3(256), 0, stream>>>(w1, W2);
  spectral_fused<<<dim3(1024), dim3(512), 0, stream>>>(x, W2, o);
}